// Round 12
// baseline (198.425 us; speedup 1.0000x reference)
//
#include <hip/hip_runtime.h>
#include <hip/hip_bf16.h>

// HeteroLinear fused forward on gfx950: out[i] = x[i] @ W[tv[i]] + b[tv[i]]
// N=131072, IN=OUT=256, T=8, tv sorted. HBM floor ~256 MB -> ~41 us.
// R12: no LDS, no barriers, 4-wave blocks ("R4 done right").
// Evidence: 8-wave blocks NEVER co-reside (occupancy ~19% whenever
// VGPR>=104, all rounds); timed dur tracks barrier count (R8 2bar=72.3,
// R10 4bar=76.3, R11 9bar=79.7). So: remove both constraints.
//  - W[t] slice in REGISTERS per wave (64 VGPR, from L2-resident wT, loaded
//    once per block; boundary reloads <=7 chip-wide) -- R11's proven element
//  - x loaded DIRECT from global, 16-row x 128B coalesced segments, dist-1
//    raw prefetch -- R8's proven element
//  - wave = 32 rows x 32 cols, acc[2][2]=16 VGPR; ~116 VGPR total -> 4
//    waves/SIMD, 16 waves/CU, 4 independent blocks/CU, zero sync points
//  - block = 4 waves sharing 32 rows (L1), 128 cols; 2 col-groups chip-wide
//    (2x x-read absorbed by L3: x=128MB < 256MB)

#define NROWS 131072
#define KD 256
#define ND 256
#define BR 32                       // rows per block
#define NBLK ((NROWS / BR) * 2)     // 4096 row-groups x 2 col-groups = 8192

typedef __attribute__((ext_vector_type(8))) short short8;
typedef __attribute__((ext_vector_type(4))) float f32x4;
typedef __attribute__((ext_vector_type(4))) float flt4;

__device__ inline unsigned short f2bf(float f) {
    unsigned int u = __float_as_uint(f);
    u += 0x7FFFu + ((u >> 16) & 1u);   // RNE
    return (unsigned short)(u >> 16);
}

// ---- weight prep: wT[t][n][k] = bf16(w[t][k][n]) ----
__global__ __launch_bounds__(256) void prep_weights(const float* __restrict__ w,
                                                    unsigned short* __restrict__ wT) {
    __shared__ unsigned short L[8][264];
    const int t  = blockIdx.x >> 5;
    const int k0 = (blockIdx.x & 31) * 8;
    const int tid = threadIdx.x;

    #pragma unroll
    for (int i = 0; i < 2; ++i) {
        int idx = i * 256 + tid;
        int kr  = idx >> 6;
        int nq  = idx & 63;
        const flt4* src = (const flt4*)(w + ((size_t)t * 256 + k0 + kr) * 256);
        flt4 v = src[nq];
        #pragma unroll
        for (int j = 0; j < 4; ++j) L[kr][nq * 4 + j] = f2bf(v[j]);
    }
    __syncthreads();

    int n = tid;
    short8 v;
    #pragma unroll
    for (int j = 0; j < 8; ++j) v[j] = (short)L[j][n];
    *(short8*)(wT + ((size_t)t * 256 + n) * 256 + k0) = v;
}

// ---- main GEMM: no LDS, no barriers, W in regs, x direct ----
__global__ __launch_bounds__(256) void hetero_gemm(
        const float* __restrict__ x, const int* __restrict__ tv,
        const unsigned short* __restrict__ wT, const float* __restrict__ bias,
        float* __restrict__ out) {
    const int tid  = threadIdx.x;
    const int lane = tid & 63;
    const int wv   = tid >> 6;               // 4 waves
    const int cl   = lane & 15;
    const int kg   = lane >> 4;
    const int rg   = blockIdx.x >> 1;        // row-group (32 rows)
    const int cb   = (blockIdx.x & 1) * 128; // col-group base
    const int r0   = rg * BR;
    const int c0   = cb + wv * 32;           // wave's 32 cols

    const int tmin = tv[r0];
    const int tmax = tv[r0 + BR - 1];
    const int ty0  = tv[r0 + cl];            // type of row m=0
    const int ty1  = tv[r0 + 16 + cl];       // type of row m=1

    // ---- W[t] register slice: 16 x short8 = 64 VGPR ----
    short8 Wf[8][2];
    int wt = -1;
    auto loadWT = [&](int t) {
        const unsigned short* Wt = wT + (size_t)t * (KD * ND);
        #pragma unroll
        for (int ks = 0; ks < 8; ++ks)
            #pragma unroll
            for (int n = 0; n < 2; ++n)
                Wf[ks][n] = *(const short8*)(Wt + (size_t)(c0 + n * 16 + cl) * KD
                                             + ks * 32 + kg * 8);
        wt = t;
    };
    loadWT(tmin);

    // x row pointers for this lane (rows m*16+cl), k-offset kg*8
    const float* xr0 = x + (size_t)(r0 + cl) * KD + kg * 8;
    const float* xr1 = x + (size_t)(r0 + 16 + cl) * KD + kg * 8;

    for (int t = tmin; t <= tmax; ++t) {
        if (t != wt) loadWT(t);              // rare (<=7 boundary blocks)

        f32x4 zero = {0.f, 0.f, 0.f, 0.f};
        f32x4 acc[2][2];
        acc[0][0] = zero; acc[0][1] = zero;
        acc[1][0] = zero; acc[1][1] = zero;

        // raw prefetch of ks=0
        f32x4 xv[4];
        xv[0] = *(const f32x4*)(xr0);
        xv[1] = *(const f32x4*)(xr0 + 4);
        xv[2] = *(const f32x4*)(xr1);
        xv[3] = *(const f32x4*)(xr1 + 4);

        #pragma unroll
        for (int ks = 0; ks < 8; ++ks) {
            f32x4 xn[4];
            if (ks < 7) {                    // dist-1 raw prefetch
                xn[0] = *(const f32x4*)(xr0 + (ks + 1) * 32);
                xn[1] = *(const f32x4*)(xr0 + (ks + 1) * 32 + 4);
                xn[2] = *(const f32x4*)(xr1 + (ks + 1) * 32);
                xn[3] = *(const f32x4*)(xr1 + (ks + 1) * 32 + 4);
            }
            short8 a[2];
            #pragma unroll
            for (int m = 0; m < 2; ++m) {
                #pragma unroll
                for (int j = 0; j < 4; ++j) {
                    a[m][j]     = (short)f2bf(xv[2 * m][j]);
                    a[m][4 + j] = (short)f2bf(xv[2 * m + 1][j]);
                }
            }
            #pragma unroll
            for (int m = 0; m < 2; ++m) {
                acc[m][0] = __builtin_amdgcn_mfma_f32_16x16x32_bf16(Wf[ks][0], a[m], acc[m][0], 0, 0, 0);
                acc[m][1] = __builtin_amdgcn_mfma_f32_16x16x32_bf16(Wf[ks][1], a[m], acc[m][1], 0, 0, 0);
            }
            xv[0] = xn[0]; xv[1] = xn[1]; xv[2] = xn[2]; xv[3] = xn[3];
        }

        // epilogue: acc[m][n][j] = out[r0+m*16+cl][c0+n*16+kg*4+j]
        #pragma unroll
        for (int m = 0; m < 2; ++m) {
            int tym = (m == 0) ? ty0 : ty1;
            if (tym == t) {
                float* orow = out + (size_t)(r0 + m * 16 + cl) * ND + c0 + kg * 4;
                f32x4 bv0 = *(const f32x4*)(bias + (size_t)t * ND + c0 + kg * 4);
                f32x4 bv1 = *(const f32x4*)(bias + (size_t)t * ND + c0 + 16 + kg * 4);
                *(f32x4*)(orow)      = acc[m][0] + bv0;
                *(f32x4*)(orow + 16) = acc[m][1] + bv1;
            }
        }
    }
}

extern "C" void kernel_launch(void* const* d_in, const int* in_sizes, int n_in,
                              void* d_out, int out_size, void* d_ws, size_t ws_size,
                              hipStream_t stream) {
    const float* x    = (const float*)d_in[0];
    const int*   tv   = (const int*)d_in[1];
    const float* w    = (const float*)d_in[2];
    const float* bias = (const float*)d_in[3];
    float* out = (float*)d_out;
    unsigned short* wT = (unsigned short*)d_ws;   // 8*256*256*2 = 1 MiB

    prep_weights<<<dim3(256), dim3(256), 0, stream>>>(w, wT);
    hetero_gemm<<<dim3(NBLK), dim3(256), 0, stream>>>(x, tv, wT, bias, out);
}

// Round 13
// 66.804 us; speedup vs baseline: 2.9703x; 2.9703x over previous
//
#include <hip/hip_runtime.h>
#include <hip/hip_bf16.h>

// HeteroLinear fused forward on gfx950: out[i] = x[i] @ W[tv[i]] + b[tv[i]]
// N=131072, IN=OUT=256, T=8, tv sorted. HBM floor ~200-256 MB -> ~41 us.
// R13 = R8 (best: 72.3 us) + ONE lever: dist-2 raw-f32x4 x-prefetch.
// R8's residual: dist-1 gives ~250 cy cover vs ~500 cy HBM latency at
// 2 waves/SIMD -> x-stream duty ~50%. Two-buffer consume-then-reissue
// doubles cover. Raw (uncvt) buffers keep pressure at ~120 VGPR < 128 cap.
// Everything else identical to R8 (W[t] in 128 KB LDS staged once/block,
// swizzled ds_reads, two col-halves acc[2][8], plain f32x4 stores).

#define NROWS 131072
#define KD 256
#define ND 256
#define BM 256                      // rows per block
#define NBLK (NROWS / BM)           // 512

typedef __attribute__((ext_vector_type(8))) short short8;
typedef __attribute__((ext_vector_type(4))) float f32x4;
typedef __attribute__((ext_vector_type(4))) float flt4;

typedef __attribute__((address_space(3))) unsigned int lds_u32_t;
typedef __attribute__((address_space(1))) unsigned int glb_u32_t;

__device__ inline unsigned short f2bf(float f) {
    unsigned int u = __float_as_uint(f);
    u += 0x7FFFu + ((u >> 16) & 1u);   // RNE
    return (unsigned short)(u >> 16);
}

// ---- weight prep: wT[t][n][k] = bf16(w[t][k][n]) ----
__global__ __launch_bounds__(256) void prep_weights(const float* __restrict__ w,
                                                    unsigned short* __restrict__ wT) {
    __shared__ unsigned short L[8][264];
    const int t  = blockIdx.x >> 5;
    const int k0 = (blockIdx.x & 31) * 8;
    const int tid = threadIdx.x;

    #pragma unroll
    for (int i = 0; i < 2; ++i) {
        int idx = i * 256 + tid;
        int kr  = idx >> 6;
        int nq  = idx & 63;
        const flt4* src = (const flt4*)(w + ((size_t)t * 256 + k0 + kr) * 256);
        flt4 v = src[nq];
        #pragma unroll
        for (int j = 0; j < 4; ++j) L[kr][nq * 4 + j] = f2bf(v[j]);
    }
    __syncthreads();

    int n = tid;
    short8 v;
    #pragma unroll
    for (int j = 0; j < 8; ++j) v[j] = (short)L[j][n];
    *(short8*)(wT + ((size_t)t * 256 + n) * 256 + k0) = v;
}

// ---- main GEMM ----
__global__ __launch_bounds__(512) void hetero_gemm(
        const float* __restrict__ x, const int* __restrict__ tv,
        const unsigned short* __restrict__ wT, const float* __restrict__ bias,
        float* __restrict__ out) {
    // W[t] tile, bf16, [col][k], 512 B per col-row, XOR-swizzled 16B chunks:
    // LDS chunk c of col holds global k-chunk c ^ (col&7).
    __shared__ short Bs[BM * KD];            // 128 KiB

    const int tid  = threadIdx.x;
    const int lane = tid & 63;
    const int wv   = tid >> 6;               // 8 waves
    const int cl   = lane & 15;
    const int kg   = lane >> 4;
    const int r0   = blockIdx.x * BM;
    const int rw   = r0 + wv * 32;           // wave's 32-row strip

    const int tmin = tv[r0];
    const int tmax = tv[r0 + BM - 1];
    const int ty0  = tv[rw + cl];            // type of row (m=0)
    const int ty1  = tv[rw + 16 + cl];       // type of row (m=1)
    const int s    = cl & 7;                 // swizzle key (col&7 == cl&7)

    // per-lane x row pointers (rows rw+m*16+cl), k-offset kg*8
    const float* xr0 = x + (size_t)(rw + cl) * KD + kg * 8;
    const float* xr1 = x + (size_t)(rw + 16 + cl) * KD + kg * 8;

    for (int t = tmin; t <= tmax; ++t) {
        if (t > tmin) __syncthreads();       // prev-pass reads done before overwrite

        // ---- stage W[t] -> LDS: 8192 16B chunks, 16 wave-rounds ----
        {
            const unsigned short* Wt = wT + (size_t)t * (KD * ND);
            #pragma unroll
            for (int rnd = 0; rnd < 16; ++rnd) {
                int i   = rnd * 512 + tid;   // chunk index 0..8191 (per-lane)
                int col = i >> 5;
                int c   = i & 31;
                int sc  = c ^ (col & 7);     // source-side swizzle
                const unsigned short* gp = Wt + col * KD + sc * 8;
                __builtin_amdgcn_global_load_lds(
                    (const glb_u32_t*)gp,
                    (lds_u32_t*)((char*)Bs + (size_t)(rnd * 512 + wv * 64) * 16),
                    16, 0, 0);
            }
        }
        __syncthreads();                     // drain DMA; tile ready

        // ---- compute in two col-halves: acc 64 VGPR per half ----
        #pragma unroll
        for (int half = 0; half < 2; ++half) {
            const int c0 = half * 128;

            f32x4 zero = {0.f, 0.f, 0.f, 0.f};
            f32x4 acc[2][8];
            #pragma unroll
            for (int m = 0; m < 2; ++m)
                #pragma unroll
                for (int n = 0; n < 8; ++n) acc[m][n] = zero;

            // dist-2 raw prefetch: two 4x-f32x4 buffers, consume-then-reissue
            f32x4 xbA[4], xbB[4];
            xbA[0] = *(const f32x4*)(xr0);          // ks=0
            xbA[1] = *(const f32x4*)(xr0 + 4);
            xbA[2] = *(const f32x4*)(xr1);
            xbA[3] = *(const f32x4*)(xr1 + 4);
            xbB[0] = *(const f32x4*)(xr0 + 32);     // ks=1
            xbB[1] = *(const f32x4*)(xr0 + 36);
            xbB[2] = *(const f32x4*)(xr1 + 32);
            xbB[3] = *(const f32x4*)(xr1 + 36);

            auto step = [&](f32x4 (&xb)[4], int ks) {
                // cvt consumed buffer -> a-frags (waits only on its own loads)
                short8 a[2];
                #pragma unroll
                for (int m = 0; m < 2; ++m) {
                    #pragma unroll
                    for (int j = 0; j < 4; ++j) {
                        a[m][j]     = (short)f2bf(xb[2 * m][j]);
                        a[m][4 + j] = (short)f2bf(xb[2 * m + 1][j]);
                    }
                }
                // reissue freed buffer for ks+2 (dist-2 cover ~2 ks-steps)
                if (ks + 2 < 8) {
                    xb[0] = *(const f32x4*)(xr0 + (ks + 2) * 32);
                    xb[1] = *(const f32x4*)(xr0 + (ks + 2) * 32 + 4);
                    xb[2] = *(const f32x4*)(xr1 + (ks + 2) * 32);
                    xb[3] = *(const f32x4*)(xr1 + (ks + 2) * 32 + 4);
                }
                #pragma unroll
                for (int n = 0; n < 8; ++n) {
                    int lc = c0 + n * 16 + cl;            // col
                    int kc = ((ks << 2) | kg) ^ s;        // swizzled 16B chunk
                    short8 b = *(const short8*)((char*)Bs + (size_t)lc * 512 + (kc << 4));
                    // swapped operands: D[w-col][x-row]
                    acc[0][n] = __builtin_amdgcn_mfma_f32_16x16x32_bf16(b, a[0], acc[0][n], 0, 0, 0);
                    acc[1][n] = __builtin_amdgcn_mfma_f32_16x16x32_bf16(b, a[1], acc[1][n], 0, 0, 0);
                }
            };
            step(xbA, 0); step(xbB, 1); step(xbA, 2); step(xbB, 3);
            step(xbA, 4); step(xbB, 5); step(xbA, 6); step(xbB, 7);

            // ---- epilogue: rows rw+m*16+cl, cols c0+n*16+kg*4 (plain stores) ----
            #pragma unroll
            for (int m = 0; m < 2; ++m) {
                int tym = (m == 0) ? ty0 : ty1;
                if (tym == t) {
                    float* orow = out + (size_t)(rw + m * 16 + cl) * ND + c0 + kg * 4;
                    #pragma unroll
                    for (int n = 0; n < 8; ++n) {
                        f32x4 bv = *(const f32x4*)(bias + (size_t)t * ND + c0 + n * 16 + kg * 4);
                        *(f32x4*)(orow + n * 16) = acc[m][n] + bv;
                    }
                }
            }
        }
    }
}

extern "C" void kernel_launch(void* const* d_in, const int* in_sizes, int n_in,
                              void* d_out, int out_size, void* d_ws, size_t ws_size,
                              hipStream_t stream) {
    const float* x    = (const float*)d_in[0];
    const int*   tv   = (const int*)d_in[1];
    const float* w    = (const float*)d_in[2];
    const float* bias = (const float*)d_in[3];
    float* out = (float*)d_out;
    unsigned short* wT = (unsigned short*)d_ws;   // 8*256*256*2 = 1 MiB

    prep_weights<<<dim3(256), dim3(256), 0, stream>>>(w, wT);
    hetero_gemm<<<dim3(NBLK), dim3(512), 0, stream>>>(x, tv, wT, bias, out);
}